// Round 10
// baseline (165.880 us; speedup 1.0000x reference)
//
#include <hip/hip_runtime.h>
#include <hip/hip_bf16.h>

#define B_   4
#define S_   1024
#define HID_ 1024
#define H_   16
#define D_   64

typedef __attribute__((ext_vector_type(4))) float f32x4;
typedef __attribute__((ext_vector_type(8))) __bf16 bf16v8;
typedef __attribute__((ext_vector_type(8))) unsigned short u16x8;
typedef __attribute__((ext_vector_type(4))) unsigned short u16x4;

#define MFMA16(a, b, c) __builtin_amdgcn_mfma_f32_16x16x32_bf16((a), (b), (c), 0, 0, 0)
#define GLOAD16(gp, lp)                                                              \
    __builtin_amdgcn_global_load_lds((const __attribute__((address_space(1))) void*)(gp), \
                                     (__attribute__((address_space(3))) void*)(lp), 16, 0, 0)

__device__ __forceinline__ unsigned short f2bs_hw(float f) {
    __bf16 h = (__bf16)f;
    return __builtin_bit_cast(unsigned short, h);
}
__device__ __forceinline__ unsigned pack2bf(float a, float b) {
    unsigned short lo = f2bs_hw(a), hi = f2bs_hw(b);
    return (unsigned)lo | ((unsigned)hi << 16);
}
__device__ __forceinline__ float bs2f(unsigned short s) {
    union { unsigned u; float f; } v; v.u = ((unsigned)s) << 16;
    return v.f;
}

// ---------------------------------------------------------------------------
// Kernel 1: merged f32 -> bf16 conversion for X, Wq, Wk, Wv, E (one launch)
// ---------------------------------------------------------------------------
__global__ void convall_kernel(const float* __restrict__ X,
                               const float* __restrict__ Wq, const float* __restrict__ Wk,
                               const float* __restrict__ Wv, const float* __restrict__ E,
                               unsigned short* __restrict__ Xb,
                               unsigned short* __restrict__ Wqb, unsigned short* __restrict__ Wkb,
                               unsigned short* __restrict__ Wvb, unsigned short* __restrict__ Eb) {
    int bid = blockIdx.x;
    const float* src;
    unsigned short* dst;
    int n4, base;
    if (bid < 4096)      { src = X;  dst = Xb;  n4 = 1048576; base = bid; }
    else if (bid < 5120) { src = Wq; dst = Wqb; n4 = 262144;  base = bid - 4096; }
    else if (bid < 6144) { src = Wk; dst = Wkb; n4 = 262144;  base = bid - 5120; }
    else if (bid < 7168) { src = Wv; dst = Wvb; n4 = 262144;  base = bid - 6144; }
    else                 { src = E;  dst = Eb;  n4 = 32752;   base = bid - 7168; }
    int i = base * 256 + threadIdx.x;
    if (i < n4) {
        float4 x = *(const float4*)(src + (size_t)i * 4);
        uint2 o;
        o.x = pack2bf(x.x, x.y);
        o.y = pack2bf(x.z, x.w);
        *(uint2*)(dst + (size_t)i * 4) = o;
    }
}

// ---------------------------------------------------------------------------
// Kernel 2: fused QKV projection GEMM (dbuf, ONE barrier per K-step)
// ---------------------------------------------------------------------------
__global__ __launch_bounds__(256)
void proj_kernel(const unsigned short* __restrict__ Xb,
                 const unsigned short* __restrict__ Wqb, const float* __restrict__ bq,
                 const unsigned short* __restrict__ Wkb, const float* __restrict__ bk,
                 const unsigned short* __restrict__ Wvb, const float* __restrict__ bv,
                 unsigned short* __restrict__ Qo, unsigned short* __restrict__ Ko,
                 unsigned short* __restrict__ Vo)
{
    __shared__ __align__(16) unsigned short Al[2][128][64];
    __shared__ __align__(16) unsigned short Bl[2][128][64];

    const int bid = blockIdx.x;
    const int tile = (bid & 7) * 96 + (bid >> 3);
    const int rt = tile / 24, ct = tile % 24;
    const int row0 = rt * 128, col0 = ct * 128;
    const int which = col0 >> 10;
    const unsigned short* Wm = (which == 0) ? Wqb : (which == 1) ? Wkb : Wvb;
    const float* bias        = (which == 0) ? bq  : (which == 1) ? bk  : bv;
    unsigned short* Out      = (which == 0) ? Qo  : (which == 1) ? Ko  : Vo;
    const int oc0 = col0 & 1023;

    const int t = threadIdx.x;
    const int lane = t & 63, w = t >> 6;
    const int wr = w >> 1, wc = w & 1;
    const int lg = lane >> 4, lc = lane & 15;

    f32x4 acc[4][4] = {};

#pragma unroll
    for (int l = 0; l < 4; ++l) {
        int idx = l * 256 + t;
        int r = idx >> 3, su = idx & 7;
        int u = su ^ (r & 7);
        GLOAD16(Xb + (size_t)(row0 + r) * 1024 + u * 8,
                &Al[0][0][0] + (size_t)(l * 256 + w * 64) * 8);
        GLOAD16(Wm + (size_t)(oc0 + r) * 1024 + u * 8,
                &Bl[0][0][0] + (size_t)(l * 256 + w * 64) * 8);
    }

    for (int it = 0; it < 16; ++it) {
        const int p = it & 1;
        __syncthreads();
        if (it < 15) {
            const int k1 = (it + 1) * 64;
#pragma unroll
            for (int l = 0; l < 4; ++l) {
                int idx = l * 256 + t;
                int r = idx >> 3, su = idx & 7;
                int u = su ^ (r & 7);
                GLOAD16(Xb + (size_t)(row0 + r) * 1024 + k1 + u * 8,
                        &Al[p ^ 1][0][0] + (size_t)(l * 256 + w * 64) * 8);
                GLOAD16(Wm + (size_t)(oc0 + r) * 1024 + k1 + u * 8,
                        &Bl[p ^ 1][0][0] + (size_t)(l * 256 + w * 64) * 8);
            }
        }
        bf16v8 af[4][2], bfg[4][2];
#pragma unroll
        for (int m = 0; m < 4; ++m)
#pragma unroll
            for (int ks = 0; ks < 2; ++ks) {
                int u = (ks * 4 + lg) ^ (lc & 7);
                af[m][ks] = *(const bf16v8*)&Al[p][wr * 64 + m * 16 + lc][u * 8];
            }
#pragma unroll
        for (int n = 0; n < 4; ++n)
#pragma unroll
            for (int ks = 0; ks < 2; ++ks) {
                int u = (ks * 4 + lg) ^ (lc & 7);
                bfg[n][ks] = *(const bf16v8*)&Bl[p][wc * 64 + n * 16 + lc][u * 8];
            }
        __builtin_amdgcn_s_setprio(1);
#pragma unroll
        for (int m = 0; m < 4; ++m)
#pragma unroll
            for (int n = 0; n < 4; ++n) {
                acc[m][n] = MFMA16(af[m][0], bfg[n][0], acc[m][n]);
                acc[m][n] = MFMA16(af[m][1], bfg[n][1], acc[m][n]);
            }
        __builtin_amdgcn_s_setprio(0);
    }

#pragma unroll
    for (int m = 0; m < 4; ++m)
#pragma unroll
        for (int n = 0; n < 4; ++n) {
            int j = oc0 + wc * 64 + n * 16 + lc;
            int hh = j >> 6, dd = j & 63;
            float bv_ = bias[j];
#pragma unroll
            for (int r = 0; r < 4; ++r) {
                int i = row0 + wr * 64 + m * 16 + lg * 4 + r;
                int bb = i >> 10, ss = i & 1023;
                float v = acc[m][n][r] + bv_;
                Out[((size_t)(bb * 16 + hh) * 1024 + ss) * 64 + dd] = f2bs_hw(v);
            }
        }
}

// ---------------------------------------------------------------------------
// Kernel 3: fused attention (R9 skeleton) with:
//  - KD band-trim: 5 tiles (ndc = 3-w+k) instead of 8
//  - QDl stride 132 (bank-tiled) + dup slots 128..131 -> imm-offset gathers
// ---------------------------------------------------------------------------
__global__ __launch_bounds__(256)
void attn_kernel(const unsigned short* __restrict__ Q,
                 const unsigned short* __restrict__ K,
                 const unsigned short* __restrict__ V,
                 const float* __restrict__ mask,
                 const unsigned short* __restrict__ Eb,
                 float* __restrict__ Out)
{
    __shared__ __align__(16) unsigned short Kl[64][64];    // unit-swizzled (u ^= row&7)
    __shared__ __align__(16) unsigned short El[128][64];   // ring (slot=d&127), swizzled
    __shared__ __align__(16) unsigned short VTl[64][72];   // col-rotated
    __shared__ __align__(16) unsigned short QDl[4][16][132]; // wave-private ring + dup 128..131
    __shared__ __align__(16) unsigned short KDl[64][132];  // [j][c], banded
    __shared__ __align__(16) unsigned Pex[4 * 16 * 36];    // P exchange
    __shared__ float maskl[64];

    const int t = threadIdx.x;
    const int lane = t & 63, w = t >> 6;
    const int lg = lane >> 4, lc = lane & 15;

    const int bid = blockIdx.x;
    const int bh = bid & 63;         // XCD grouping: same bh -> same XCD
    const int qt = bid >> 6;
    const int b = bh >> 4, h = bh & 15;
    const int i0 = qt * 64;
    const int i_loc = w * 16 + lc;

    const float C2 = 0.125f * 1.44269504089f;
    const float L2E = 1.44269504089f;

    const unsigned short* Qh = Q + (size_t)bh * S_ * D_;
    const unsigned short* Kh = K + (size_t)bh * S_ * D_;
    const unsigned short* Vh = V + (size_t)bh * S_ * D_;

    bf16v8 qf[2];
#pragma unroll
    for (int ks = 0; ks < 2; ++ks)
        qf[ks] = *(const bf16v8*)(Qh + (size_t)(i0 + i_loc) * D_ + ks * 32 + lg * 8);

    u16x8 ones_u;
#pragma unroll
    for (int e = 0; e < 8; ++e) ones_u[e] = 0x3F80;
    const bf16v8 onesf = __builtin_bit_cast(bf16v8, ones_u);

    float m_r = -1e30f;
    f32x4 lacc = (f32x4){0.f, 0.f, 0.f, 0.f};
    f32x4 ctx[4];
#pragma unroll
    for (int nd = 0; nd < 4; ++nd) ctx[nd] = (f32x4){0.f, 0.f, 0.f, 0.f};

    unsigned* PexW = &Pex[(w * 16 + lc) * 36];
    unsigned short* QDrow = &QDl[w][lc][0];
    const int keyE = lc & 7;

    for (int jt = 0; jt < 16; ++jt) {
        const int j0 = jt * 64;
        const int dbase = i0 - j0 + 960;
        __syncthreads();                        // (1) prev readers done

        // ---- stage K tile ----
#pragma unroll
        for (int l = 0; l < 2; ++l) {
            int idx = l * 256 + t;
            int r = idx >> 3, su = idx & 7;
            int u = su ^ (r & 7);
            GLOAD16(Kh + (size_t)(j0 + r) * 64 + u * 8,
                    &Kl[0][0] + (size_t)(l * 256 + w * 64) * 8);
        }
        // ---- stage V^T tile ----
        {
            int a = t & 7, rb = (t >> 3) << 1;
            int cq = a * 8;
            u16x8 v0 = *(const u16x8*)(Vh + (size_t)(j0 + rb) * 64 + cq);
            u16x8 v1 = *(const u16x8*)(Vh + (size_t)(j0 + rb + 1) * 64 + cq);
            int jst = (rb + (a << 3)) & 63;
#pragma unroll
            for (int e = 0; e < 8; ++e)
                *(unsigned*)&VTl[cq + e][jst] = (unsigned)v0[e] | ((unsigned)v1[e] << 16);
        }
        // ---- stage E window (ring) ----
        if (jt == 0) {
            const int sb0 = dbase & 127;
#pragma unroll
            for (int l = 0; l < 4; ++l) {
                int idx = l * 256 + t;
                int sl = idx >> 3, su = idx & 7;
                int u = su ^ (sl & 7);
                int dr = dbase + ((sl - sb0) & 127);
                if (dr > 2046) dr = 2046;
                GLOAD16(Eb + (size_t)dr * 64 + u * 8,
                        &El[0][0] + (size_t)(l * 256 + w * 64) * 8);
            }
        } else {
            const int sb = dbase & 127;
#pragma unroll
            for (int l = 0; l < 2; ++l) {
                int idx = l * 256 + t;
                int rl = idx >> 3, su = idx & 7;
                int u = su ^ (rl & 7);
                GLOAD16(Eb + (size_t)(dbase + rl) * 64 + u * 8,
                        &El[sb][0] + (size_t)(l * 256 + w * 64) * 8);
            }
        }
        if (t < 64) maskl[t] = mask[(size_t)b * S_ + j0 + t] * L2E;
        __syncthreads();                        // (2) staging complete

        // ---- KD band producer: 5 tiles ndc = 3-w+k ----
        bf16v8 kfa[2];
#pragma unroll
        for (int ks = 0; ks < 2; ++ks) {
            int u = (ks * 4 + lg) ^ keyE;
            kfa[ks] = *(const bf16v8*)&Kl[w * 16 + lc][u * 8];
        }
        __builtin_amdgcn_s_setprio(1);
#pragma unroll
        for (int k = 0; k < 5; ++k) {
            int ndc16 = 48 - w * 16 + k * 16;
            int sl = (dbase + ndc16 + lc) & 127;
            bf16v8 ef0 = *(const bf16v8*)&El[sl][(lg ^ keyE) * 8];
            bf16v8 ef1 = *(const bf16v8*)&El[sl][((4 + lg) ^ keyE) * 8];
            f32x4 kd = (f32x4){0.f, 0.f, 0.f, 0.f};
            kd = MFMA16(ef0, kfa[0], kd);
            kd = MFMA16(ef1, kfa[1], kd);
            uint2 pk;
            pk.x = pack2bf(kd[0], kd[1]);
            pk.y = pack2bf(kd[2], kd[3]);
            *(uint2*)&KDl[w * 16 + lc][ndc16 + lg * 4] = pk;
        }
        // ---- QD producer: new window half (4 nd; all 8 at jt=0), dup 128..131 ----
#pragma unroll
        for (int nd = 0; nd < 4; ++nd) {
            int sl = (dbase + nd * 16 + lc) & 127;
            bf16v8 ef0 = *(const bf16v8*)&El[sl][(lg ^ keyE) * 8];
            bf16v8 ef1 = *(const bf16v8*)&El[sl][((4 + lg) ^ keyE) * 8];
            f32x4 qd = (f32x4){0.f, 0.f, 0.f, 0.f};
            qd = MFMA16(ef0, qf[0], qd);
            qd = MFMA16(ef1, qf[1], qd);
            int slot0 = ((dbase & 127) + nd * 16 + lg * 4) & 127;
            uint2 qk2;
            qk2.x = pack2bf(qd[0], qd[1]);
            qk2.y = pack2bf(qd[2], qd[3]);
            *(uint2*)&QDrow[slot0] = qk2;
            if (slot0 == 0) *(uint2*)&QDrow[128] = qk2;
        }
        if (jt == 0) {
#pragma unroll
            for (int nd = 4; nd < 8; ++nd) {
                int sl = (dbase + nd * 16 + lc) & 127;
                bf16v8 ef0 = *(const bf16v8*)&El[sl][(lg ^ keyE) * 8];
                bf16v8 ef1 = *(const bf16v8*)&El[sl][((4 + lg) ^ keyE) * 8];
                f32x4 qd = (f32x4){0.f, 0.f, 0.f, 0.f};
                qd = MFMA16(ef0, qf[0], qd);
                qd = MFMA16(ef1, qf[1], qd);
                int slot0 = ((dbase & 127) + nd * 16 + lg * 4) & 127;
                uint2 qk2;
                qk2.x = pack2bf(qd[0], qd[1]);
                qk2.y = pack2bf(qd[2], qd[3]);
                *(uint2*)&QDrow[slot0] = qk2;
                if (slot0 == 0) *(uint2*)&QDrow[128] = qk2;
            }
        }
        // ---- S^T = MFMA(K, Q): reads only Kl (ready since bar 2) ----
        f32x4 s[4];
#pragma unroll
        for (int n = 0; n < 4; ++n) {
            s[n] = (f32x4){0.f, 0.f, 0.f, 0.f};
#pragma unroll
            for (int ks = 0; ks < 2; ++ks) {
                int u = (ks * 4 + lg) ^ keyE;
                bf16v8 kb = *(const bf16v8*)&Kl[n * 16 + lc][u * 8];
                s[n] = MFMA16(kb, qf[ks], s[n]);
            }
        }
        __builtin_amdgcn_s_setprio(0);
        __syncthreads();                        // (3) KDl visible

        // ---- rel gathers (imm offsets) + mask + per-lane online softmax ----
        float vmax = -1e30f;
#pragma unroll
        for (int n = 0; n < 4; ++n) {
            int jb = n * 16 + lg * 4;
            float4 mk = *(const float4*)&maskl[jb];
            int kbase = jb * 131 + i_loc + 63;
            int slot3 = (dbase + i_loc - jb + 60) & 127;     // qbase - 3
#pragma unroll
            for (int r = 0; r < 4; ++r) {
                float qdv = bs2f(QDrow[slot3 + 3 - r]);
                float kdv = bs2f((&KDl[0][0])[kbase + 131 * r]);
                float mkr = (r == 0) ? mk.x : (r == 1) ? mk.y : (r == 2) ? mk.z : mk.w;
                float val = (s[n][r] + qdv + kdv) * C2 + mkr;
                s[n][r] = val;
                vmax = fmaxf(vmax, val);
            }
        }
        vmax = fmaxf(vmax, __shfl_xor(vmax, 16));
        vmax = fmaxf(vmax, __shfl_xor(vmax, 32));

        if (__any(vmax > m_r)) {
            float mnew = fmaxf(m_r, vmax);
            float alpha = exp2f(m_r - mnew);
            m_r = mnew;
#pragma unroll
            for (int r = 0; r < 4; ++r) lacc[r] *= alpha;
#pragma unroll
            for (int nd = 0; nd < 4; ++nd)
#pragma unroll
                for (int r = 0; r < 4; ++r)
                    ctx[nd][r] *= alpha;
        }

#pragma unroll
        for (int n = 0; n < 4; ++n)
#pragma unroll
            for (int r = 0; r < 4; ++r)
                s[n][r] = exp2f(s[n][r] - m_r);

        // ---- P exchange (wave-synchronous LDS) ----
#pragma unroll
        for (int n = 0; n < 4; ++n) {
            uint2 pk;
            pk.x = pack2bf(s[n][0], s[n][1]);
            pk.y = pack2bf(s[n][2], s[n][3]);
            *(uint2*)&PexW[n * 8 + lg * 2] = pk;
        }
        bf16v8 pfB[2];
#pragma unroll
        for (int ks = 0; ks < 2; ++ks) {
            int nc = 2 * ks + (lg >> 1);
            pfB[ks] = *(const bf16v8*)&PexW[nc * 8 + (lg & 1) * 4];
        }

        // ---- l-sum + PV ----
        __builtin_amdgcn_s_setprio(1);
        lacc = MFMA16(onesf, pfB[0], lacc);
        lacc = MFMA16(onesf, pfB[1], lacc);
#pragma unroll
        for (int nd = 0; nd < 4; ++nd) {
            int vrow = nd * 16 + lc;
#pragma unroll
            for (int ks = 0; ks < 2; ++ks) {
                int jst = (ks * 32 + lg * 8 + ((vrow >> 3) << 3)) & 63;
                bf16v8 vf = *(const bf16v8*)&VTl[vrow][jst];
                ctx[nd] = MFMA16(vf, pfB[ks], ctx[nd]);
            }
        }
        __builtin_amdgcn_s_setprio(0);
    }

    // ---- epilogue ----
    float inv = 1.0f / lacc[0];
    float* outp = Out + ((size_t)(b * S_ + i0 + i_loc) * H_ + h) * D_;
#pragma unroll
    for (int nd = 0; nd < 4; ++nd) {
        float4 o;
        o.x = ctx[nd][0] * inv;
        o.y = ctx[nd][1] * inv;
        o.z = ctx[nd][2] * inv;
        o.w = ctx[nd][3] * inv;
        *(float4*)(outp + nd * 16 + lg * 4) = o;
    }
}

// ---------------------------------------------------------------------------
extern "C" void kernel_launch(void* const* d_in, const int* in_sizes, int n_in,
                              void* d_out, int out_size, void* d_ws, size_t ws_size,
                              hipStream_t stream)
{
    const float* X    = (const float*)d_in[0];
    const float* mask = (const float*)d_in[1];
    const float* Wq   = (const float*)d_in[2];
    const float* bq   = (const float*)d_in[3];
    const float* Wk   = (const float*)d_in[4];
    const float* bk   = (const float*)d_in[5];
    const float* Wv   = (const float*)d_in[6];
    const float* bv   = (const float*)d_in[7];
    const float* E    = (const float*)d_in[8];
    float* Out = (float*)d_out;

    const size_t headN = (size_t)B_ * H_ * S_ * D_;
    unsigned short* Qw  = (unsigned short*)d_ws;
    unsigned short* Kw  = Qw + headN;
    unsigned short* Vw  = Kw + headN;
    unsigned short* Ebw = Vw + headN;
    unsigned short* Xb  = Ebw + (size_t)2047 * 64;
    unsigned short* Wqb = Xb + (size_t)4096 * 1024;
    unsigned short* Wkb = Wqb + (size_t)1024 * 1024;
    unsigned short* Wvb = Wkb + (size_t)1024 * 1024;

    convall_kernel<<<dim3(7296), dim3(256), 0, stream>>>(X, Wq, Wk, Wv, E,
                                                         Xb, Wqb, Wkb, Wvb, Ebw);
    proj_kernel<<<dim3(768), dim3(256), 0, stream>>>(Xb, Wqb, bq, Wkb, bk, Wvb, bv, Qw, Kw, Vw);
    attn_kernel<<<dim3(1024), dim3(256), 0, stream>>>(Qw, Kw, Vw, mask, Ebw, Out);
}

// Round 11
// 149.340 us; speedup vs baseline: 1.1108x; 1.1108x over previous
//
#include <hip/hip_runtime.h>
#include <hip/hip_bf16.h>

#define B_   4
#define S_   1024
#define HID_ 1024
#define H_   16
#define D_   64

typedef __attribute__((ext_vector_type(4))) float f32x4;
typedef __attribute__((ext_vector_type(8))) __bf16 bf16v8;
typedef __attribute__((ext_vector_type(8))) unsigned short u16x8;
typedef __attribute__((ext_vector_type(4))) unsigned short u16x4;

#define MFMA16(a, b, c) __builtin_amdgcn_mfma_f32_16x16x32_bf16((a), (b), (c), 0, 0, 0)
#define GLOAD16(gp, lp)                                                              \
    __builtin_amdgcn_global_load_lds((const __attribute__((address_space(1))) void*)(gp), \
                                     (__attribute__((address_space(3))) void*)(lp), 16, 0, 0)

__device__ __forceinline__ unsigned short f2bs_hw(float f) {
    __bf16 h = (__bf16)f;
    return __builtin_bit_cast(unsigned short, h);
}
__device__ __forceinline__ unsigned pack2bf(float a, float b) {
    unsigned short lo = f2bs_hw(a), hi = f2bs_hw(b);
    return (unsigned)lo | ((unsigned)hi << 16);
}
__device__ __forceinline__ float bs2f(unsigned short s) {
    union { unsigned u; float f; } v; v.u = ((unsigned)s) << 16;
    return v.f;
}

// ---------------------------------------------------------------------------
// Kernel 1: merged f32 -> bf16 conversion for X, Wq, Wk, Wv, E (one launch)
// ---------------------------------------------------------------------------
__global__ void convall_kernel(const float* __restrict__ X,
                               const float* __restrict__ Wq, const float* __restrict__ Wk,
                               const float* __restrict__ Wv, const float* __restrict__ E,
                               unsigned short* __restrict__ Xb,
                               unsigned short* __restrict__ Wqb, unsigned short* __restrict__ Wkb,
                               unsigned short* __restrict__ Wvb, unsigned short* __restrict__ Eb) {
    int bid = blockIdx.x;
    const float* src;
    unsigned short* dst;
    int n4, base;
    if (bid < 4096)      { src = X;  dst = Xb;  n4 = 1048576; base = bid; }
    else if (bid < 5120) { src = Wq; dst = Wqb; n4 = 262144;  base = bid - 4096; }
    else if (bid < 6144) { src = Wk; dst = Wkb; n4 = 262144;  base = bid - 5120; }
    else if (bid < 7168) { src = Wv; dst = Wvb; n4 = 262144;  base = bid - 6144; }
    else                 { src = E;  dst = Eb;  n4 = 32752;   base = bid - 7168; }
    int i = base * 256 + threadIdx.x;
    if (i < n4) {
        float4 x = *(const float4*)(src + (size_t)i * 4);
        uint2 o;
        o.x = pack2bf(x.x, x.y);
        o.y = pack2bf(x.z, x.w);
        *(uint2*)(dst + (size_t)i * 4) = o;
    }
}

// ---------------------------------------------------------------------------
// Kernel 2: fused QKV projection GEMM (dbuf, ONE barrier per K-step)
// ---------------------------------------------------------------------------
__global__ __launch_bounds__(256)
void proj_kernel(const unsigned short* __restrict__ Xb,
                 const unsigned short* __restrict__ Wqb, const float* __restrict__ bq,
                 const unsigned short* __restrict__ Wkb, const float* __restrict__ bk,
                 const unsigned short* __restrict__ Wvb, const float* __restrict__ bv,
                 unsigned short* __restrict__ Qo, unsigned short* __restrict__ Ko,
                 unsigned short* __restrict__ Vo)
{
    __shared__ __align__(16) unsigned short Al[2][128][64];
    __shared__ __align__(16) unsigned short Bl[2][128][64];

    const int bid = blockIdx.x;
    const int tile = (bid & 7) * 96 + (bid >> 3);
    const int rt = tile / 24, ct = tile % 24;
    const int row0 = rt * 128, col0 = ct * 128;
    const int which = col0 >> 10;
    const unsigned short* Wm = (which == 0) ? Wqb : (which == 1) ? Wkb : Wvb;
    const float* bias        = (which == 0) ? bq  : (which == 1) ? bk  : bv;
    unsigned short* Out      = (which == 0) ? Qo  : (which == 1) ? Ko  : Vo;
    const int oc0 = col0 & 1023;

    const int t = threadIdx.x;
    const int lane = t & 63, w = t >> 6;
    const int wr = w >> 1, wc = w & 1;
    const int lg = lane >> 4, lc = lane & 15;

    f32x4 acc[4][4] = {};

#pragma unroll
    for (int l = 0; l < 4; ++l) {
        int idx = l * 256 + t;
        int r = idx >> 3, su = idx & 7;
        int u = su ^ (r & 7);
        GLOAD16(Xb + (size_t)(row0 + r) * 1024 + u * 8,
                &Al[0][0][0] + (size_t)(l * 256 + w * 64) * 8);
        GLOAD16(Wm + (size_t)(oc0 + r) * 1024 + u * 8,
                &Bl[0][0][0] + (size_t)(l * 256 + w * 64) * 8);
    }

    for (int it = 0; it < 16; ++it) {
        const int p = it & 1;
        __syncthreads();
        if (it < 15) {
            const int k1 = (it + 1) * 64;
#pragma unroll
            for (int l = 0; l < 4; ++l) {
                int idx = l * 256 + t;
                int r = idx >> 3, su = idx & 7;
                int u = su ^ (r & 7);
                GLOAD16(Xb + (size_t)(row0 + r) * 1024 + k1 + u * 8,
                        &Al[p ^ 1][0][0] + (size_t)(l * 256 + w * 64) * 8);
                GLOAD16(Wm + (size_t)(oc0 + r) * 1024 + k1 + u * 8,
                        &Bl[p ^ 1][0][0] + (size_t)(l * 256 + w * 64) * 8);
            }
        }
        bf16v8 af[4][2], bfg[4][2];
#pragma unroll
        for (int m = 0; m < 4; ++m)
#pragma unroll
            for (int ks = 0; ks < 2; ++ks) {
                int u = (ks * 4 + lg) ^ (lc & 7);
                af[m][ks] = *(const bf16v8*)&Al[p][wr * 64 + m * 16 + lc][u * 8];
            }
#pragma unroll
        for (int n = 0; n < 4; ++n)
#pragma unroll
            for (int ks = 0; ks < 2; ++ks) {
                int u = (ks * 4 + lg) ^ (lc & 7);
                bfg[n][ks] = *(const bf16v8*)&Bl[p][wc * 64 + n * 16 + lc][u * 8];
            }
        __builtin_amdgcn_s_setprio(1);
#pragma unroll
        for (int m = 0; m < 4; ++m)
#pragma unroll
            for (int n = 0; n < 4; ++n) {
                acc[m][n] = MFMA16(af[m][0], bfg[n][0], acc[m][n]);
                acc[m][n] = MFMA16(af[m][1], bfg[n][1], acc[m][n]);
            }
        __builtin_amdgcn_s_setprio(0);
    }

#pragma unroll
    for (int m = 0; m < 4; ++m)
#pragma unroll
        for (int n = 0; n < 4; ++n) {
            int j = oc0 + wc * 64 + n * 16 + lc;
            int hh = j >> 6, dd = j & 63;
            float bv_ = bias[j];
#pragma unroll
            for (int r = 0; r < 4; ++r) {
                int i = row0 + wr * 64 + m * 16 + lg * 4 + r;
                int bb = i >> 10, ss = i & 1023;
                float v = acc[m][n][r] + bv_;
                Out[((size_t)(bb * 16 + hh) * 1024 + ss) * 64 + dd] = f2bs_hw(v);
            }
        }
}

// ---------------------------------------------------------------------------
// Kernel 3: fused attention — R9 skeleton (measured 115.9 µs) + T14 prefetch:
// K/E global_load_lds + V/mask reg-loads for jt+1 issued after barrier (3),
// hidden under gather/softmax/PV. Kl/El are dead post-bar3 (proven above).
// ---------------------------------------------------------------------------
__global__ __launch_bounds__(256)
void attn_kernel(const unsigned short* __restrict__ Q,
                 const unsigned short* __restrict__ K,
                 const unsigned short* __restrict__ V,
                 const float* __restrict__ mask,
                 const unsigned short* __restrict__ Eb,
                 float* __restrict__ Out)
{
    __shared__ __align__(16) unsigned short Kl[64][64];    // unit-swizzled (u ^= row&7)
    __shared__ __align__(16) unsigned short El[128][64];   // ring (slot=d&127), swizzled
    __shared__ __align__(16) unsigned short VTl[64][72];   // col-rotated
    __shared__ __align__(16) unsigned short QDl[4][16][136]; // wave-private [w][i=lc][slot]
    __shared__ __align__(16) unsigned short KDl[64][132];  // [j][c]
    __shared__ __align__(16) unsigned Pex[4 * 16 * 36];    // P exchange
    __shared__ float maskl[64];

    const int t = threadIdx.x;
    const int lane = t & 63, w = t >> 6;
    const int lg = lane >> 4, lc = lane & 15;

    const int bid = blockIdx.x;
    const int bh = bid & 63;         // XCD grouping: same bh -> same XCD
    const int qt = bid >> 6;
    const int b = bh >> 4, h = bh & 15;
    const int i0 = qt * 64;
    const int i_loc = w * 16 + lc;

    const float C2 = 0.125f * 1.44269504089f;
    const float L2E = 1.44269504089f;

    const unsigned short* Qh = Q + (size_t)bh * S_ * D_;
    const unsigned short* Kh = K + (size_t)bh * S_ * D_;
    const unsigned short* Vh = V + (size_t)bh * S_ * D_;

    bf16v8 qf[2];
#pragma unroll
    for (int ks = 0; ks < 2; ++ks)
        qf[ks] = *(const bf16v8*)(Qh + (size_t)(i0 + i_loc) * D_ + ks * 32 + lg * 8);

    u16x8 ones_u;
#pragma unroll
    for (int e = 0; e < 8; ++e) ones_u[e] = 0x3F80;
    const bf16v8 onesf = __builtin_bit_cast(bf16v8, ones_u);

    float m_r = -1e30f;
    f32x4 lacc = (f32x4){0.f, 0.f, 0.f, 0.f};
    f32x4 ctx[4];
#pragma unroll
    for (int nd = 0; nd < 4; ++nd) ctx[nd] = (f32x4){0.f, 0.f, 0.f, 0.f};

    unsigned* PexW = &Pex[(w * 16 + lc) * 36];

    // V^T staging constants
    const int va = t & 7, vrb = (t >> 3) << 1;
    const int vcq = va * 8;
    const int vjst = (vrb + (va << 3)) & 63;

    // ---- prologue: stage jt=0 K/E (async to LDS); V + mask to regs ----
    u16x8 v0c, v1c;
    float mkc;
    {
#pragma unroll
        for (int l = 0; l < 2; ++l) {
            int idx = l * 256 + t;
            int r = idx >> 3, su = idx & 7;
            int u = su ^ (r & 7);
            GLOAD16(Kh + (size_t)r * 64 + u * 8,
                    &Kl[0][0] + (size_t)(l * 256 + w * 64) * 8);
        }
        const int db0 = i0 + 960;
        const int sb0 = db0 & 127;
#pragma unroll
        for (int l = 0; l < 4; ++l) {
            int idx = l * 256 + t;
            int sl = idx >> 3, su = idx & 7;
            int u = su ^ (sl & 7);
            int dr = db0 + ((sl - sb0) & 127);
            if (dr > 2046) dr = 2046;
            GLOAD16(Eb + (size_t)dr * 64 + u * 8,
                    &El[0][0] + (size_t)(l * 256 + w * 64) * 8);
        }
        v0c = *(const u16x8*)(Vh + (size_t)vrb * 64 + vcq);
        v1c = *(const u16x8*)(Vh + (size_t)(vrb + 1) * 64 + vcq);
        mkc = (t < 64) ? mask[(size_t)b * S_ + t] * L2E : 0.f;
    }

    for (int jt = 0; jt < 16; ++jt) {
        const int j0 = jt * 64;
        const int dbase = i0 - j0 + 960;
        __syncthreads();                        // (1) prev PV done reading VTl

        // ---- write V^T + mask from carried regs ----
#pragma unroll
        for (int e = 0; e < 8; ++e)
            *(unsigned*)&VTl[vcq + e][vjst] = (unsigned)v0c[e] | ((unsigned)v1c[e] << 16);
        if (t < 64) maskl[t] = mkc;
        __syncthreads();                        // (2) VTl/maskl visible; K/E gloads drained

        // ---- merged rel GEMMs: KD (8 nd) + QD (new half), shared E frags ----
        bf16v8 kfa[2];
#pragma unroll
        for (int ks = 0; ks < 2; ++ks) {
            int u = (ks * 4 + lg) ^ (lc & 7);
            kfa[ks] = *(const bf16v8*)&Kl[w * 16 + lc][u * 8];
        }
        __builtin_amdgcn_s_setprio(1);
#pragma unroll
        for (int nd = 0; nd < 8; ++nd) {
            int sl = (dbase + nd * 16 + lc) & 127;
            int u0 = lg ^ (lc & 7);
            int u1 = (4 + lg) ^ (lc & 7);
            bf16v8 ef0 = *(const bf16v8*)&El[sl][u0 * 8];
            bf16v8 ef1 = *(const bf16v8*)&El[sl][u1 * 8];
            f32x4 kd = (f32x4){0.f, 0.f, 0.f, 0.f};
            kd = MFMA16(ef0, kfa[0], kd);
            kd = MFMA16(ef1, kfa[1], kd);
            uint2 pk;
            pk.x = pack2bf(kd[0], kd[1]);
            pk.y = pack2bf(kd[2], kd[3]);
            *(uint2*)&KDl[w * 16 + lc][nd * 16 + lg * 4] = pk;
            if (nd < 4 || jt == 0) {
                f32x4 qd = (f32x4){0.f, 0.f, 0.f, 0.f};
                qd = MFMA16(ef0, qf[0], qd);
                qd = MFMA16(ef1, qf[1], qd);
                int slot0 = ((dbase & 127) + nd * 16 + lg * 4) & 127;
                uint2 qk2;
                qk2.x = pack2bf(qd[0], qd[1]);
                qk2.y = pack2bf(qd[2], qd[3]);
                *(uint2*)&QDl[w][lc][slot0] = qk2;
            }
        }
        // ---- S^T = MFMA(K, Q): reads only Kl (ready since bar 2) ----
        f32x4 s[4];
#pragma unroll
        for (int n = 0; n < 4; ++n) {
            s[n] = (f32x4){0.f, 0.f, 0.f, 0.f};
#pragma unroll
            for (int ks = 0; ks < 2; ++ks) {
                int u = (ks * 4 + lg) ^ (lc & 7);
                bf16v8 kb = *(const bf16v8*)&Kl[n * 16 + lc][u * 8];
                s[n] = MFMA16(kb, qf[ks], s[n]);
            }
        }
        __builtin_amdgcn_s_setprio(0);
        __syncthreads();                        // (3) KDl/QDl visible; Kl/El now dead

        // ---- prefetch jt+1: K/E async-to-LDS, V/mask to regs (T14) ----
        if (jt < 15) {
            const int j0n = j0 + 64;
            const int dbn = dbase - 64;
            const int sbn = dbn & 127;
#pragma unroll
            for (int l = 0; l < 2; ++l) {
                int idx = l * 256 + t;
                int r = idx >> 3, su = idx & 7;
                int u = su ^ (r & 7);
                GLOAD16(Kh + (size_t)(j0n + r) * 64 + u * 8,
                        &Kl[0][0] + (size_t)(l * 256 + w * 64) * 8);
            }
#pragma unroll
            for (int l = 0; l < 2; ++l) {
                int idx = l * 256 + t;
                int rl = idx >> 3, su = idx & 7;
                int u = su ^ (rl & 7);
                GLOAD16(Eb + (size_t)(dbn + rl) * 64 + u * 8,
                        &El[sbn][0] + (size_t)(l * 256 + w * 64) * 8);
            }
            v0c = *(const u16x8*)(Vh + (size_t)(j0n + vrb) * 64 + vcq);
            v1c = *(const u16x8*)(Vh + (size_t)(j0n + vrb + 1) * 64 + vcq);
            mkc = (t < 64) ? mask[(size_t)b * S_ + j0n + t] * L2E : 0.f;
        }

        // ---- rel gathers + mask + per-lane online softmax ----
        const unsigned short* QDw = &QDl[w][lc][0];
        float vmax = -1e30f;
#pragma unroll
        for (int n = 0; n < 4; ++n) {
            int jb = n * 16 + lg * 4;
            float4 mk = *(const float4*)&maskl[jb];
            int kbase = jb * 131 + i_loc + 63;
            int qbase = dbase + i_loc - jb + 63;
#pragma unroll
            for (int r = 0; r < 4; ++r) {
                float qdv = bs2f(QDw[(qbase - r) & 127]);
                float kdv = bs2f((&KDl[0][0])[kbase + 131 * r]);
                float mkr = (r == 0) ? mk.x : (r == 1) ? mk.y : (r == 2) ? mk.z : mk.w;
                float val = (s[n][r] + qdv + kdv) * C2 + mkr;
                s[n][r] = val;
                vmax = fmaxf(vmax, val);
            }
        }
        vmax = fmaxf(vmax, __shfl_xor(vmax, 16));
        vmax = fmaxf(vmax, __shfl_xor(vmax, 32));

        if (__any(vmax > m_r)) {
            float mnew = fmaxf(m_r, vmax);
            float alpha = exp2f(m_r - mnew);
            m_r = mnew;
#pragma unroll
            for (int r = 0; r < 4; ++r) lacc[r] *= alpha;
#pragma unroll
            for (int nd = 0; nd < 4; ++nd)
#pragma unroll
                for (int r = 0; r < 4; ++r)
                    ctx[nd][r] *= alpha;
        }

#pragma unroll
        for (int n = 0; n < 4; ++n)
#pragma unroll
            for (int r = 0; r < 4; ++r)
                s[n][r] = exp2f(s[n][r] - m_r);

        // ---- P exchange (wave-synchronous LDS) ----
#pragma unroll
        for (int n = 0; n < 4; ++n) {
            uint2 pk;
            pk.x = pack2bf(s[n][0], s[n][1]);
            pk.y = pack2bf(s[n][2], s[n][3]);
            *(uint2*)&PexW[n * 8 + lg * 2] = pk;
        }
        bf16v8 pfB[2];
#pragma unroll
        for (int ks = 0; ks < 2; ++ks) {
            int nc = 2 * ks + (lg >> 1);
            pfB[ks] = *(const bf16v8*)&PexW[nc * 8 + (lg & 1) * 4];
        }

        // ---- l-sum + PV ----
        __builtin_amdgcn_s_setprio(1);
        lacc = MFMA16(onesf, pfB[0], lacc);
        lacc = MFMA16(onesf, pfB[1], lacc);
#pragma unroll
        for (int nd = 0; nd < 4; ++nd) {
            int vrow = nd * 16 + lc;
#pragma unroll
            for (int ks = 0; ks < 2; ++ks) {
                int jst = (ks * 32 + lg * 8 + ((vrow >> 3) << 3)) & 63;
                bf16v8 vf = *(const bf16v8*)&VTl[vrow][jst];
                ctx[nd] = MFMA16(vf, pfB[ks], ctx[nd]);
            }
        }
        __builtin_amdgcn_s_setprio(0);
    }

    // ---- epilogue ----
    float inv = 1.0f / lacc[0];
    float* outp = Out + ((size_t)(b * S_ + i0 + i_loc) * H_ + h) * D_;
#pragma unroll
    for (int nd = 0; nd < 4; ++nd) {
        float4 o;
        o.x = ctx[nd][0] * inv;
        o.y = ctx[nd][1] * inv;
        o.z = ctx[nd][2] * inv;
        o.w = ctx[nd][3] * inv;
        *(float4*)(outp + nd * 16 + lg * 4) = o;
    }
}

// ---------------------------------------------------------------------------
extern "C" void kernel_launch(void* const* d_in, const int* in_sizes, int n_in,
                              void* d_out, int out_size, void* d_ws, size_t ws_size,
                              hipStream_t stream)
{
    const float* X    = (const float*)d_in[0];
    const float* mask = (const float*)d_in[1];
    const float* Wq   = (const float*)d_in[2];
    const float* bq   = (const float*)d_in[3];
    const float* Wk   = (const float*)d_in[4];
    const float* bk   = (const float*)d_in[5];
    const float* Wv   = (const float*)d_in[6];
    const float* bv   = (const float*)d_in[7];
    const float* E    = (const float*)d_in[8];
    float* Out = (float*)d_out;

    const size_t headN = (size_t)B_ * H_ * S_ * D_;
    unsigned short* Qw  = (unsigned short*)d_ws;
    unsigned short* Kw  = Qw + headN;
    unsigned short* Vw  = Kw + headN;
    unsigned short* Ebw = Vw + headN;
    unsigned short* Xb  = Ebw + (size_t)2047 * 64;
    unsigned short* Wqb = Xb + (size_t)4096 * 1024;
    unsigned short* Wkb = Wqb + (size_t)1024 * 1024;
    unsigned short* Wvb = Wkb + (size_t)1024 * 1024;

    convall_kernel<<<dim3(7296), dim3(256), 0, stream>>>(X, Wq, Wk, Wv, E,
                                                         Xb, Wqb, Wkb, Wvb, Ebw);
    proj_kernel<<<dim3(768), dim3(256), 0, stream>>>(Xb, Wqb, bq, Wkb, bk, Wvb, bv, Qw, Kw, Vw);
    attn_kernel<<<dim3(1024), dim3(256), 0, stream>>>(Qw, Kw, Vw, mask, Ebw, Out);
}

// Round 12
// 149.073 us; speedup vs baseline: 1.1127x; 1.0018x over previous
//
#include <hip/hip_runtime.h>
#include <hip/hip_bf16.h>

#define B_   4
#define S_   1024
#define HID_ 1024
#define H_   16
#define D_   64

typedef __attribute__((ext_vector_type(4))) float f32x4;
typedef __attribute__((ext_vector_type(8))) __bf16 bf16v8;
typedef __attribute__((ext_vector_type(8))) unsigned short u16x8;
typedef __attribute__((ext_vector_type(4))) unsigned short u16x4;

#define MFMA16(a, b, c) __builtin_amdgcn_mfma_f32_16x16x32_bf16((a), (b), (c), 0, 0, 0)
#define GLOAD16(gp, lp)                                                              \
    __builtin_amdgcn_global_load_lds((const __attribute__((address_space(1))) void*)(gp), \
                                     (__attribute__((address_space(3))) void*)(lp), 16, 0, 0)

__device__ __forceinline__ unsigned short f2bs_hw(float f) {
    __bf16 h = (__bf16)f;
    return __builtin_bit_cast(unsigned short, h);
}
__device__ __forceinline__ unsigned pack2bf(float a, float b) {
    unsigned short lo = f2bs_hw(a), hi = f2bs_hw(b);
    return (unsigned)lo | ((unsigned)hi << 16);
}
__device__ __forceinline__ float bs2f(unsigned short s) {
    union { unsigned u; float f; } v; v.u = ((unsigned)s) << 16;
    return v.f;
}

// ---------------------------------------------------------------------------
// Kernel 1: merged f32 -> bf16 conversion for X, Wq, Wk, Wv, E (one launch)
// ---------------------------------------------------------------------------
__global__ void convall_kernel(const float* __restrict__ X,
                               const float* __restrict__ Wq, const float* __restrict__ Wk,
                               const float* __restrict__ Wv, const float* __restrict__ E,
                               unsigned short* __restrict__ Xb,
                               unsigned short* __restrict__ Wqb, unsigned short* __restrict__ Wkb,
                               unsigned short* __restrict__ Wvb, unsigned short* __restrict__ Eb) {
    int bid = blockIdx.x;
    const float* src;
    unsigned short* dst;
    int n4, base;
    if (bid < 4096)      { src = X;  dst = Xb;  n4 = 1048576; base = bid; }
    else if (bid < 5120) { src = Wq; dst = Wqb; n4 = 262144;  base = bid - 4096; }
    else if (bid < 6144) { src = Wk; dst = Wkb; n4 = 262144;  base = bid - 5120; }
    else if (bid < 7168) { src = Wv; dst = Wvb; n4 = 262144;  base = bid - 6144; }
    else                 { src = E;  dst = Eb;  n4 = 32752;   base = bid - 7168; }
    int i = base * 256 + threadIdx.x;
    if (i < n4) {
        float4 x = *(const float4*)(src + (size_t)i * 4);
        uint2 o;
        o.x = pack2bf(x.x, x.y);
        o.y = pack2bf(x.z, x.w);
        *(uint2*)(dst + (size_t)i * 4) = o;
    }
}

// ---------------------------------------------------------------------------
// Kernel 2: fused QKV projection GEMM (dbuf, ONE barrier per K-step)
// ---------------------------------------------------------------------------
__global__ __launch_bounds__(256)
void proj_kernel(const unsigned short* __restrict__ Xb,
                 const unsigned short* __restrict__ Wqb, const float* __restrict__ bq,
                 const unsigned short* __restrict__ Wkb, const float* __restrict__ bk,
                 const unsigned short* __restrict__ Wvb, const float* __restrict__ bv,
                 unsigned short* __restrict__ Qo, unsigned short* __restrict__ Ko,
                 unsigned short* __restrict__ Vo)
{
    __shared__ __align__(16) unsigned short Al[2][128][64];
    __shared__ __align__(16) unsigned short Bl[2][128][64];

    const int bid = blockIdx.x;
    const int tile = (bid & 7) * 96 + (bid >> 3);
    const int rt = tile / 24, ct = tile % 24;
    const int row0 = rt * 128, col0 = ct * 128;
    const int which = col0 >> 10;
    const unsigned short* Wm = (which == 0) ? Wqb : (which == 1) ? Wkb : Wvb;
    const float* bias        = (which == 0) ? bq  : (which == 1) ? bk  : bv;
    unsigned short* Out      = (which == 0) ? Qo  : (which == 1) ? Ko  : Vo;
    const int oc0 = col0 & 1023;

    const int t = threadIdx.x;
    const int lane = t & 63, w = t >> 6;
    const int wr = w >> 1, wc = w & 1;
    const int lg = lane >> 4, lc = lane & 15;

    f32x4 acc[4][4] = {};

#pragma unroll
    for (int l = 0; l < 4; ++l) {
        int idx = l * 256 + t;
        int r = idx >> 3, su = idx & 7;
        int u = su ^ (r & 7);
        GLOAD16(Xb + (size_t)(row0 + r) * 1024 + u * 8,
                &Al[0][0][0] + (size_t)(l * 256 + w * 64) * 8);
        GLOAD16(Wm + (size_t)(oc0 + r) * 1024 + u * 8,
                &Bl[0][0][0] + (size_t)(l * 256 + w * 64) * 8);
    }

    for (int it = 0; it < 16; ++it) {
        const int p = it & 1;
        __syncthreads();
        if (it < 15) {
            const int k1 = (it + 1) * 64;
#pragma unroll
            for (int l = 0; l < 4; ++l) {
                int idx = l * 256 + t;
                int r = idx >> 3, su = idx & 7;
                int u = su ^ (r & 7);
                GLOAD16(Xb + (size_t)(row0 + r) * 1024 + k1 + u * 8,
                        &Al[p ^ 1][0][0] + (size_t)(l * 256 + w * 64) * 8);
                GLOAD16(Wm + (size_t)(oc0 + r) * 1024 + k1 + u * 8,
                        &Bl[p ^ 1][0][0] + (size_t)(l * 256 + w * 64) * 8);
            }
        }
        bf16v8 af[4][2], bfg[4][2];
#pragma unroll
        for (int m = 0; m < 4; ++m)
#pragma unroll
            for (int ks = 0; ks < 2; ++ks) {
                int u = (ks * 4 + lg) ^ (lc & 7);
                af[m][ks] = *(const bf16v8*)&Al[p][wr * 64 + m * 16 + lc][u * 8];
            }
#pragma unroll
        for (int n = 0; n < 4; ++n)
#pragma unroll
            for (int ks = 0; ks < 2; ++ks) {
                int u = (ks * 4 + lg) ^ (lc & 7);
                bfg[n][ks] = *(const bf16v8*)&Bl[p][wc * 64 + n * 16 + lc][u * 8];
            }
        __builtin_amdgcn_s_setprio(1);
#pragma unroll
        for (int m = 0; m < 4; ++m)
#pragma unroll
            for (int n = 0; n < 4; ++n) {
                acc[m][n] = MFMA16(af[m][0], bfg[n][0], acc[m][n]);
                acc[m][n] = MFMA16(af[m][1], bfg[n][1], acc[m][n]);
            }
        __builtin_amdgcn_s_setprio(0);
    }

#pragma unroll
    for (int m = 0; m < 4; ++m)
#pragma unroll
        for (int n = 0; n < 4; ++n) {
            int j = oc0 + wc * 64 + n * 16 + lc;
            int hh = j >> 6, dd = j & 63;
            float bv_ = bias[j];
#pragma unroll
            for (int r = 0; r < 4; ++r) {
                int i = row0 + wr * 64 + m * 16 + lg * 4 + r;
                int bb = i >> 10, ss = i & 1023;
                float v = acc[m][n][r] + bv_;
                Out[((size_t)(bb * 16 + hh) * 1024 + ss) * 64 + dd] = f2bs_hw(v);
            }
        }
}

// ---------------------------------------------------------------------------
// Kernel 3: fused attention — R11 skeleton with TWO barriers per jt:
//  (1) loop top: prev readers done; prefetched K/E gloads drained (vmcnt0)
//  (3) post-producer: KDl/QDl AND VTl/maskl visible
// VTl/mask written right after (1) from carried regs; S^T hoisted early.
// ---------------------------------------------------------------------------
__global__ __launch_bounds__(256)
void attn_kernel(const unsigned short* __restrict__ Q,
                 const unsigned short* __restrict__ K,
                 const unsigned short* __restrict__ V,
                 const float* __restrict__ mask,
                 const unsigned short* __restrict__ Eb,
                 float* __restrict__ Out)
{
    __shared__ __align__(16) unsigned short Kl[64][64];    // unit-swizzled (u ^= row&7)
    __shared__ __align__(16) unsigned short El[128][64];   // ring (slot=d&127), swizzled
    __shared__ __align__(16) unsigned short VTl[64][72];   // col-rotated
    __shared__ __align__(16) unsigned short QDl[4][16][136]; // wave-private [w][i=lc][slot]
    __shared__ __align__(16) unsigned short KDl[64][132];  // [j][c]
    __shared__ __align__(16) unsigned Pex[4 * 16 * 36];    // P exchange
    __shared__ float maskl[64];

    const int t = threadIdx.x;
    const int lane = t & 63, w = t >> 6;
    const int lg = lane >> 4, lc = lane & 15;

    const int bid = blockIdx.x;
    const int bh = bid & 63;         // XCD grouping: same bh -> same XCD
    const int qt = bid >> 6;
    const int b = bh >> 4, h = bh & 15;
    const int i0 = qt * 64;
    const int i_loc = w * 16 + lc;

    const float C2 = 0.125f * 1.44269504089f;
    const float L2E = 1.44269504089f;

    const unsigned short* Qh = Q + (size_t)bh * S_ * D_;
    const unsigned short* Kh = K + (size_t)bh * S_ * D_;
    const unsigned short* Vh = V + (size_t)bh * S_ * D_;

    bf16v8 qf[2];
#pragma unroll
    for (int ks = 0; ks < 2; ++ks)
        qf[ks] = *(const bf16v8*)(Qh + (size_t)(i0 + i_loc) * D_ + ks * 32 + lg * 8);

    u16x8 ones_u;
#pragma unroll
    for (int e = 0; e < 8; ++e) ones_u[e] = 0x3F80;
    const bf16v8 onesf = __builtin_bit_cast(bf16v8, ones_u);

    float m_r = -1e30f;
    f32x4 lacc = (f32x4){0.f, 0.f, 0.f, 0.f};
    f32x4 ctx[4];
#pragma unroll
    for (int nd = 0; nd < 4; ++nd) ctx[nd] = (f32x4){0.f, 0.f, 0.f, 0.f};

    unsigned* PexW = &Pex[(w * 16 + lc) * 36];

    // V^T staging constants
    const int va = t & 7, vrb = (t >> 3) << 1;
    const int vcq = va * 8;
    const int vjst = (vrb + (va << 3)) & 63;

    // ---- prologue: stage jt=0 K/E (async to LDS); V + mask to regs ----
    u16x8 v0c, v1c;
    float mkc;
    {
#pragma unroll
        for (int l = 0; l < 2; ++l) {
            int idx = l * 256 + t;
            int r = idx >> 3, su = idx & 7;
            int u = su ^ (r & 7);
            GLOAD16(Kh + (size_t)r * 64 + u * 8,
                    &Kl[0][0] + (size_t)(l * 256 + w * 64) * 8);
        }
        const int db0 = i0 + 960;
        const int sb0 = db0 & 127;
#pragma unroll
        for (int l = 0; l < 4; ++l) {
            int idx = l * 256 + t;
            int sl = idx >> 3, su = idx & 7;
            int u = su ^ (sl & 7);
            int dr = db0 + ((sl - sb0) & 127);
            if (dr > 2046) dr = 2046;
            GLOAD16(Eb + (size_t)dr * 64 + u * 8,
                    &El[0][0] + (size_t)(l * 256 + w * 64) * 8);
        }
        v0c = *(const u16x8*)(Vh + (size_t)vrb * 64 + vcq);
        v1c = *(const u16x8*)(Vh + (size_t)(vrb + 1) * 64 + vcq);
        mkc = (t < 64) ? mask[(size_t)b * S_ + t] * L2E : 0.f;
    }

    for (int jt = 0; jt < 16; ++jt) {
        const int j0 = jt * 64;
        const int dbase = i0 - j0 + 960;
        __syncthreads();                        // (1) prev readers done; gloads drained

        // ---- write V^T + mask from carried regs (visible at (3)) ----
#pragma unroll
        for (int e = 0; e < 8; ++e)
            *(unsigned*)&VTl[vcq + e][vjst] = (unsigned)v0c[e] | ((unsigned)v1c[e] << 16);
        if (t < 64) maskl[t] = mkc;

        // ---- kfa + S^T = MFMA(K, Q): Kl ready since (1) ----
        bf16v8 kfa[2];
#pragma unroll
        for (int ks = 0; ks < 2; ++ks) {
            int u = (ks * 4 + lg) ^ (lc & 7);
            kfa[ks] = *(const bf16v8*)&Kl[w * 16 + lc][u * 8];
        }
        f32x4 s[4];
        __builtin_amdgcn_s_setprio(1);
#pragma unroll
        for (int n = 0; n < 4; ++n) {
            s[n] = (f32x4){0.f, 0.f, 0.f, 0.f};
#pragma unroll
            for (int ks = 0; ks < 2; ++ks) {
                int u = (ks * 4 + lg) ^ (lc & 7);
                bf16v8 kb = *(const bf16v8*)&Kl[n * 16 + lc][u * 8];
                s[n] = MFMA16(kb, qf[ks], s[n]);
            }
        }

        // ---- merged rel GEMMs: KD (8 nd) + QD (new half), shared E frags ----
#pragma unroll
        for (int nd = 0; nd < 8; ++nd) {
            int sl = (dbase + nd * 16 + lc) & 127;
            int u0 = lg ^ (lc & 7);
            int u1 = (4 + lg) ^ (lc & 7);
            bf16v8 ef0 = *(const bf16v8*)&El[sl][u0 * 8];
            bf16v8 ef1 = *(const bf16v8*)&El[sl][u1 * 8];
            f32x4 kd = (f32x4){0.f, 0.f, 0.f, 0.f};
            kd = MFMA16(ef0, kfa[0], kd);
            kd = MFMA16(ef1, kfa[1], kd);
            uint2 pk;
            pk.x = pack2bf(kd[0], kd[1]);
            pk.y = pack2bf(kd[2], kd[3]);
            *(uint2*)&KDl[w * 16 + lc][nd * 16 + lg * 4] = pk;
            if (nd < 4 || jt == 0) {
                f32x4 qd = (f32x4){0.f, 0.f, 0.f, 0.f};
                qd = MFMA16(ef0, qf[0], qd);
                qd = MFMA16(ef1, qf[1], qd);
                int slot0 = ((dbase & 127) + nd * 16 + lg * 4) & 127;
                uint2 qk2;
                qk2.x = pack2bf(qd[0], qd[1]);
                qk2.y = pack2bf(qd[2], qd[3]);
                *(uint2*)&QDl[w][lc][slot0] = qk2;
            }
        }
        __builtin_amdgcn_s_setprio(0);
        __syncthreads();                        // (3) KDl/QDl/VTl/maskl visible; Kl/El dead

        // ---- prefetch jt+1: K/E async-to-LDS, V/mask to regs (T14) ----
        if (jt < 15) {
            const int j0n = j0 + 64;
            const int dbn = dbase - 64;
            const int sbn = dbn & 127;
#pragma unroll
            for (int l = 0; l < 2; ++l) {
                int idx = l * 256 + t;
                int r = idx >> 3, su = idx & 7;
                int u = su ^ (r & 7);
                GLOAD16(Kh + (size_t)(j0n + r) * 64 + u * 8,
                        &Kl[0][0] + (size_t)(l * 256 + w * 64) * 8);
            }
#pragma unroll
            for (int l = 0; l < 2; ++l) {
                int idx = l * 256 + t;
                int rl = idx >> 3, su = idx & 7;
                int u = su ^ (rl & 7);
                GLOAD16(Eb + (size_t)(dbn + rl) * 64 + u * 8,
                        &El[sbn][0] + (size_t)(l * 256 + w * 64) * 8);
            }
            v0c = *(const u16x8*)(Vh + (size_t)(j0n + vrb) * 64 + vcq);
            v1c = *(const u16x8*)(Vh + (size_t)(j0n + vrb + 1) * 64 + vcq);
            mkc = (t < 64) ? mask[(size_t)b * S_ + j0n + t] * L2E : 0.f;
        }

        // ---- rel gathers + mask + per-lane online softmax ----
        const unsigned short* QDw = &QDl[w][lc][0];
        float vmax = -1e30f;
#pragma unroll
        for (int n = 0; n < 4; ++n) {
            int jb = n * 16 + lg * 4;
            float4 mk = *(const float4*)&maskl[jb];
            int kbase = jb * 131 + i_loc + 63;
            int qbase = dbase + i_loc - jb + 63;
#pragma unroll
            for (int r = 0; r < 4; ++r) {
                float qdv = bs2f(QDw[(qbase - r) & 127]);
                float kdv = bs2f((&KDl[0][0])[kbase + 131 * r]);
                float mkr = (r == 0) ? mk.x : (r == 1) ? mk.y : (r == 2) ? mk.z : mk.w;
                float val = (s[n][r] + qdv + kdv) * C2 + mkr;
                s[n][r] = val;
                vmax = fmaxf(vmax, val);
            }
        }
        vmax = fmaxf(vmax, __shfl_xor(vmax, 16));
        vmax = fmaxf(vmax, __shfl_xor(vmax, 32));

        if (__any(vmax > m_r)) {
            float mnew = fmaxf(m_r, vmax);
            float alpha = exp2f(m_r - mnew);
            m_r = mnew;
#pragma unroll
            for (int r = 0; r < 4; ++r) lacc[r] *= alpha;
#pragma unroll
            for (int nd = 0; nd < 4; ++nd)
#pragma unroll
                for (int r = 0; r < 4; ++r)
                    ctx[nd][r] *= alpha;
        }

#pragma unroll
        for (int n = 0; n < 4; ++n)
#pragma unroll
            for (int r = 0; r < 4; ++r)
                s[n][r] = exp2f(s[n][r] - m_r);

        // ---- P exchange (wave-synchronous LDS) ----
#pragma unroll
        for (int n = 0; n < 4; ++n) {
            uint2 pk;
            pk.x = pack2bf(s[n][0], s[n][1]);
            pk.y = pack2bf(s[n][2], s[n][3]);
            *(uint2*)&PexW[n * 8 + lg * 2] = pk;
        }
        bf16v8 pfB[2];
#pragma unroll
        for (int ks = 0; ks < 2; ++ks) {
            int nc = 2 * ks + (lg >> 1);
            pfB[ks] = *(const bf16v8*)&PexW[nc * 8 + (lg & 1) * 4];
        }

        // ---- l-sum + PV ----
        __builtin_amdgcn_s_setprio(1);
        lacc = MFMA16(onesf, pfB[0], lacc);
        lacc = MFMA16(onesf, pfB[1], lacc);
#pragma unroll
        for (int nd = 0; nd < 4; ++nd) {
            int vrow = nd * 16 + lc;
#pragma unroll
            for (int ks = 0; ks < 2; ++ks) {
                int jst = (ks * 32 + lg * 8 + ((vrow >> 3) << 3)) & 63;
                bf16v8 vf = *(const bf16v8*)&VTl[vrow][jst];
                ctx[nd] = MFMA16(vf, pfB[ks], ctx[nd]);
            }
        }
        __builtin_amdgcn_s_setprio(0);
    }

    // ---- epilogue ----
    float inv = 1.0f / lacc[0];
    float* outp = Out + ((size_t)(b * S_ + i0 + i_loc) * H_ + h) * D_;
#pragma unroll
    for (int nd = 0; nd < 4; ++nd) {
        float4 o;
        o.x = ctx[nd][0] * inv;
        o.y = ctx[nd][1] * inv;
        o.z = ctx[nd][2] * inv;
        o.w = ctx[nd][3] * inv;
        *(float4*)(outp + nd * 16 + lg * 4) = o;
    }
}

// ---------------------------------------------------------------------------
extern "C" void kernel_launch(void* const* d_in, const int* in_sizes, int n_in,
                              void* d_out, int out_size, void* d_ws, size_t ws_size,
                              hipStream_t stream)
{
    const float* X    = (const float*)d_in[0];
    const float* mask = (const float*)d_in[1];
    const float* Wq   = (const float*)d_in[2];
    const float* bq   = (const float*)d_in[3];
    const float* Wk   = (const float*)d_in[4];
    const float* bk   = (const float*)d_in[5];
    const float* Wv   = (const float*)d_in[6];
    const float* bv   = (const float*)d_in[7];
    const float* E    = (const float*)d_in[8];
    float* Out = (float*)d_out;

    const size_t headN = (size_t)B_ * H_ * S_ * D_;
    unsigned short* Qw  = (unsigned short*)d_ws;
    unsigned short* Kw  = Qw + headN;
    unsigned short* Vw  = Kw + headN;
    unsigned short* Ebw = Vw + headN;
    unsigned short* Xb  = Ebw + (size_t)2047 * 64;
    unsigned short* Wqb = Xb + (size_t)4096 * 1024;
    unsigned short* Wkb = Wqb + (size_t)1024 * 1024;
    unsigned short* Wvb = Wkb + (size_t)1024 * 1024;

    convall_kernel<<<dim3(7296), dim3(256), 0, stream>>>(X, Wq, Wk, Wv, E,
                                                         Xb, Wqb, Wkb, Wvb, Ebw);
    proj_kernel<<<dim3(768), dim3(256), 0, stream>>>(Xb, Wqb, bq, Wkb, bk, Wvb, bv, Qw, Kw, Vw);
    attn_kernel<<<dim3(1024), dim3(256), 0, stream>>>(Qw, Kw, Vw, mask, Ebw, Out);
}